// Round 6
// baseline (400.398 us; speedup 1.0000x reference)
//
#include <hip/hip_runtime.h>
#include <hip/hip_fp16.h>
#include <math.h>

#define N_NODES 100000
#define N_BASE  5000
#define N_EDGES 3200000
#define NBKT    391       // dest buckets of 256 nodes
#define CAPB    9472      // csr slots per bucket (mean 8184, sigma 90 -> +14 sigma)
#define EPB     4096      // edges per k_bucket block
#define GEB     782       // ceil(N_EDGES / EPB)

__device__ inline unsigned pkh(float a, float b) {
    return (unsigned)__half_as_ushort(__float2half_rn(a)) |
           ((unsigned)__half_as_ushort(__float2half_rn(b)) << 16);
}

__device__ inline unsigned hadd2u(unsigned a, unsigned b) {
    __half2 r = __hadd2(*(__half2*)&a, *(__half2*)&b);
    return *(unsigned*)&r;
}

// ---------------------------------------------------------------------------
// k_initg: gcur[b] = b*CAPB, bins = 0
// ---------------------------------------------------------------------------
__global__ __launch_bounds__(512) void k_initg(int* __restrict__ gcur, float* __restrict__ bins) {
    int t = threadIdx.x;
    if (t < NBKT) gcur[t] = t * CAPB;
    if (t < 64) bins[t] = 0.0f;
}

// ---------------------------------------------------------------------------
// k_bucket: 782 blocks x 4096 edges x 512 threads; LDS position-sort then
// run-linear global writes (round-5 verified).
// ---------------------------------------------------------------------------
__global__ __launch_bounds__(512) void k_bucket(const int* __restrict__ row, const int* __restrict__ col,
                                                int* __restrict__ gcur, unsigned* __restrict__ csr) {
    __shared__ int hist[NBKT], gbase[NBKT], curi[NBKT], excl[NBKT];
    __shared__ int sc[512];
    __shared__ unsigned sdst[EPB];     // packed (d&255)<<17 | src, sorted by bucket
    __shared__ int sadr[EPB];          // final global csr address per slot
    int t = threadIdx.x;
    int e0 = blockIdx.x * EPB;
    int cnt = (N_EDGES - e0 < EPB) ? (N_EDGES - e0) : EPB;
    for (int k = t; k < NBKT; k += 512) hist[k] = 0;
    __syncthreads();
    for (int j = t; j < cnt; j += 512) atomicAdd(&hist[col[e0 + j] >> 8], 1);
    __syncthreads();
    sc[t] = (t < NBKT) ? hist[t] : 0;
    __syncthreads();
    for (int off = 1; off < 512; off <<= 1) {
        int v = (t >= off) ? sc[t - off] : 0;
        __syncthreads();
        sc[t] += v;
        __syncthreads();
    }
    if (t < NBKT) {
        int e = sc[t] - hist[t];
        excl[t] = e;
        curi[t] = e;
        gbase[t] = (hist[t] > 0) ? atomicAdd(&gcur[t], hist[t]) : 0;
    }
    __syncthreads();
    for (int j = t; j < cnt; j += 512) {
        int d = col[e0 + j];           // L2-warm re-read
        int s = row[e0 + j];
        int b = d >> 8;
        int pos = atomicAdd(&curi[b], 1);              // pos in [excl[b], excl[b]+hist[b])
        sdst[pos] = ((unsigned)(d & 255) << 17) | (unsigned)s;
        sadr[pos] = gbase[b] + (pos - excl[b]);
    }
    __syncthreads();
    for (int j = t; j < cnt; j += 512) csr[sadr[j]] = sdst[j];   // run-linear writes
}

// ---------------------------------------------------------------------------
// k_sort: one block per bucket, 1024 threads; LDS counting sort (verified).
// ---------------------------------------------------------------------------
__global__ __launch_bounds__(1024) void k_sort(const int* __restrict__ gcur, unsigned* __restrict__ csr,
                                               int* __restrict__ rs, int* __restrict__ re,
                                               float* __restrict__ dinv) {
    __shared__ unsigned stage[CAPB];
    __shared__ int hist[256], offs[256], cur[256];
    int t = threadIdx.x, b = blockIdx.x;
    int base = b * CAPB;
    int cnt = gcur[b] - base;
    if (t < 256) hist[t] = 0;
    for (int j = t; j < cnt; j += 1024) stage[j] = csr[base + j];
    __syncthreads();
    for (int j = t; j < cnt; j += 1024) atomicAdd(&hist[stage[j] >> 17], 1);
    __syncthreads();
    if (t < 256) offs[t] = hist[t];
    __syncthreads();
    for (int off = 1; off < 256; off <<= 1) {
        int v = 0;
        if (t < 256 && t >= off) v = offs[t - off];
        __syncthreads();
        if (t < 256) offs[t] += v;
        __syncthreads();
    }
    if (t < 256) {
        int excl = offs[t] - hist[t];
        cur[t] = excl;
        int node = b * 256 + t;
        if (node < N_NODES) {
            rs[node] = base + excl;
            re[node] = base + excl + hist[t];
            dinv[node] = rsqrtf((float)(hist[t] + 1));   // +1 self loop
        }
    }
    __syncthreads();
    for (int j = t; j < cnt; j += 1024) {
        unsigned p = stage[j];
        int slot = atomicAdd(&cur[p >> 17], 1);
        csr[base + slot] = p & 0x1FFFFu;             // pure src
    }
}

// ---------------------------------------------------------------------------
// k_ab_h: bb = [x1 | tile(x2)] @ W4^T + b4  (float4 stores, f32)
//         h0 = dinv * (Wg @ [relu(x1@W1^T+b1) | bb])   (fp16 stores)
//         bins += W3[15:34].bb   (iteration-invariant output part)
// ---------------------------------------------------------------------------
__global__ __launch_bounds__(256) void k_ab_h(const float* __restrict__ x1, const float* __restrict__ x2,
                                              const float* __restrict__ W1, const float* __restrict__ b1,
                                              const float* __restrict__ W4, const float* __restrict__ b4,
                                              const float* __restrict__ Wg, const float* __restrict__ W3,
                                              const float* __restrict__ dinv,
                                              float* __restrict__ bb, __half* __restrict__ h0,
                                              float* __restrict__ bins) {
    __shared__ float sW1[225], sb1[15], sW4[361], sb4[19], sWg[510], sW3b[19];
    for (int t = threadIdx.x; t < 225; t += 256) sW1[t] = W1[t];
    for (int t = threadIdx.x; t < 361; t += 256) sW4[t] = W4[t];
    for (int t = threadIdx.x; t < 510; t += 256) sWg[t] = Wg[t];
    if (threadIdx.x < 15) sb1[threadIdx.x] = b1[threadIdx.x];
    if (threadIdx.x < 19) { sb4[threadIdx.x] = b4[threadIdx.x]; sW3b[threadIdx.x] = W3[15 + threadIdx.x]; }
    __syncthreads();
    int i = blockIdx.x * 256 + threadIdx.x;
    bool valid = i < N_NODES;
    int ii = valid ? i : 0;
    float x[15];
#pragma unroll
    for (int k = 0; k < 15; k++) x[k] = x1[(size_t)ii * 15 + k];
    float xt[4];
    int ib = ii % N_BASE;
#pragma unroll
    for (int k = 0; k < 4; k++) xt[k] = x2[(size_t)ib * 4 + k];
    float in[34];
    float bp = 0.0f;
#pragma unroll
    for (int o = 0; o < 19; o++) {
        float s = sb4[o];
#pragma unroll
        for (int k = 0; k < 15; k++) s += x[k] * sW4[o * 19 + k];
#pragma unroll
        for (int k = 0; k < 4; k++) s += xt[k] * sW4[o * 19 + 15 + k];
        in[15 + o] = s;
        bp += s * sW3b[o];
    }
#pragma unroll
    for (int o = 0; o < 15; o++) {
        float s = sb1[o];
#pragma unroll
        for (int k = 0; k < 15; k++) s += x[k] * sW1[o * 15 + k];
        in[o] = fmaxf(s, 0.0f);
    }
    float dn = dinv[ii];
    if (valid) {
        float4* bbp = (float4*)(bb + (size_t)ii * 20);
        bbp[0] = make_float4(in[15], in[16], in[17], in[18]);
        bbp[1] = make_float4(in[19], in[20], in[21], in[22]);
        bbp[2] = make_float4(in[23], in[24], in[25], in[26]);
        bbp[3] = make_float4(in[27], in[28], in[29], in[30]);
        bbp[4] = make_float4(in[31], in[32], in[33], 0.0f);   // [19] pad, never consumed
        float hv[15];
#pragma unroll
        for (int o = 0; o < 15; o++) {
            float s = 0.0f;
#pragma unroll
            for (int k = 0; k < 34; k++) s += in[k] * sWg[o * 34 + k];
            hv[o] = s * dn;
        }
        unsigned hu[8];
#pragma unroll
        for (int k = 0; k < 7; k++) hu[k] = pkh(hv[2 * k], hv[2 * k + 1]);
        hu[7] = pkh(hv[14], 0.0f);                            // ch 15 pad, always 0
        uint4* hp = (uint4*)(h0 + (size_t)ii * 16);
        hp[0] = make_uint4(hu[0], hu[1], hu[2], hu[3]);
        hp[1] = make_uint4(hu[4], hu[5], hu[6], hu[7]);
    }
    float val = valid ? bp : 0.0f;
#pragma unroll
    for (int off = 32; off > 0; off >>= 1) val += __shfl_down(val, off, 64);
    __shared__ float wsum[4];
    if ((threadIdx.x & 63) == 0) wsum[threadIdx.x >> 6] = val;
    __syncthreads();
    if (threadIdx.x == 0) atomicAdd(&bins[blockIdx.x & 63], wsum[0] + wsum[1] + wsum[2] + wsum[3]);
}

// ---------------------------------------------------------------------------
// k_gather (round 6): dwordx4 gathers (2 lanes/edge: es=lane>>1, half=lane&1;
// lane covers channels [8*half, 8*half+8) = dwords half*4..half*4+3 of the
// 32B row) + fp16 pk_add accumulation + uniform skip of the second 32-edge
// half when deg<=32 (54% of nodes, lim is wave-uniform).
//   VMEM instrs/64 edges: 9 -> 3;  VALU: ~60 -> ~25 per lane.
// Reduce: half2 reduce-scatter over lane bits 1..5 (send-the-discard-half),
// final mapping pair(lane) = 4*(lane&1) + 2*((lane>>1)&1) + ((lane>>2)&1);
// lanes 0..7 cover all 8 dword-pairs bijectively.
// Epilogue: round-4-verified k-split, but in[k<15] comes from per-wave LDS
// sa[wid][16] (broadcast reads) instead of parity shfls.
// Self row: init acc from hp4[node] on the es==0 lanes (counted once).
// ---------------------------------------------------------------------------
__global__ __launch_bounds__(1024) void k_gather(const int* __restrict__ rs, const int* __restrict__ re,
                                                 const unsigned* __restrict__ csr,
                                                 const __half* __restrict__ h_in,
                                                 const float* __restrict__ dinv,
                                                 const float* __restrict__ bb,
                                                 const float* __restrict__ Wg,
                                                 const float* __restrict__ bg,
                                                 const float* __restrict__ W3,
                                                 __half* __restrict__ h_out,
                                                 float* __restrict__ bins, int last) {
    __shared__ float sWg[544], sbg[16], sW3[16];
    __shared__ float sa[16][16];
    __shared__ float ws2[16];
    int t = threadIdx.x;
    for (int k = t; k < 544; k += 1024) sWg[k] = (k < 510) ? Wg[k] : 0.0f;
    if (t < 16) { sbg[t] = (t < 15) ? bg[t] : 0.0f; sW3[t] = (t < 15) ? W3[t] : 0.0f; }
    __syncthreads();
    int wid = t >> 6;
    int node = blockIdx.x * 16 + wid;
    int lane = t & 63, es = lane >> 1, half = lane & 1;
    int start = rs[node];
    int deg = re[node] - start;
    const uint4* hp4 = (const uint4*)h_in;                 // one row = 2 uint4 (32B)
    // init acc with the self row (es==0 lanes only -> counted exactly once)
    uint4 sv = make_uint4(0u, 0u, 0u, 0u);
    if (es == 0) sv = hp4[(size_t)node * 2 + half];
    unsigned a0 = sv.x, a1 = sv.y, a2 = sv.z, a3 = sv.w;
    for (int base = 0; base < deg; base += 64) {
        int rem = deg - base;
        int lim = rem < 64 ? rem : 64;                     // wave-uniform
        unsigned ce = 0;
        if (lane < lim) ce = csr[start + base + lane];
        unsigned pa = __shfl(ce, es, 64);
        uint4 va = make_uint4(0u, 0u, 0u, 0u);
        if (es < lim) va = hp4[(size_t)pa * 2 + half];
        if (lim > 32) {                                    // uniform branch
            unsigned pb = __shfl(ce, es + 32, 64);
            uint4 vb = make_uint4(0u, 0u, 0u, 0u);
            if (es + 32 < lim) vb = hp4[(size_t)pb * 2 + half];
            a0 = hadd2u(a0, va.x); a1 = hadd2u(a1, va.y);
            a2 = hadd2u(a2, va.z); a3 = hadd2u(a3, va.w);
            a0 = hadd2u(a0, vb.x); a1 = hadd2u(a1, vb.y);
            a2 = hadd2u(a2, vb.z); a3 = hadd2u(a3, vb.w);
        } else {
            a0 = hadd2u(a0, va.x); a1 = hadd2u(a1, va.y);
            a2 = hadd2u(a2, va.z); a3 = hadd2u(a3, va.w);
        }
    }
    // reduce-scatter over lanes (bits 1..5 hold replicas of each half-group).
    // xor 2: keep 2 dwords (sel2 chooses pairs {0,1} vs {2,3}); send the rest.
    int sel2 = (lane >> 1) & 1;
    unsigned s0 = sel2 ? a0 : a2;                          // send = discard half
    unsigned s1 = sel2 ? a1 : a3;
    unsigned k0 = sel2 ? a2 : a0;
    unsigned k1 = sel2 ? a3 : a1;
    k0 = hadd2u(k0, __shfl_xor(s0, 2, 64));
    k1 = hadd2u(k1, __shfl_xor(s1, 2, 64));
    // xor 4: keep 1 dword (sel4 chooses which)
    int sel4 = (lane >> 2) & 1;
    unsigned sd = sel4 ? k0 : k1;
    unsigned kk = sel4 ? k1 : k0;
    kk = hadd2u(kk, __shfl_xor(sd, 4, 64));
    // xor 8,16,32: plain allreduce on the single dword
    kk = hadd2u(kk, __shfl_xor(kk, 8, 64));
    kk = hadd2u(kk, __shfl_xor(kk, 16, 64));
    kk = hadd2u(kk, __shfl_xor(kk, 32, 64));
    // lane's dword pair index (== dword index in the row); lanes 0..7 bijective
    int pr = 4 * half + 2 * sel2 + sel4;
    float2 fsum = __half22float2(*(__half2*)&kk);
    float dn = dinv[node];
    float avx = fmaxf(dn * fsum.x + sbg[2 * pr], 0.0f);        // a[2pr]
    float avy = fmaxf(dn * fsum.y + sbg[2 * pr + 1], 0.0f);    // a[2pr+1]; pr==7 -> ch15 = 0
    if (lane < 8) { sa[wid][2 * pr] = avx; sa[wid][2 * pr + 1] = avy; }
    __syncthreads();
    if (!last) {
        int c2e = lane & 7, p = lane >> 3;
        int o0 = 2 * c2e;
        float inv0 = sa[wid][p];                               // k0 = p (<15)
        float inv1 = (p < 7) ? sa[wid][p + 8] : bb[(size_t)node * 20 + 0];  // k1 = p+8; p==7 -> in[15]
        float s0e = inv0 * sWg[o0 * 34 + p]       + inv1 * sWg[o0 * 34 + p + 8];
        float s1e = inv0 * sWg[(o0 + 1) * 34 + p] + inv1 * sWg[(o0 + 1) * 34 + p + 8];
#pragma unroll
        for (int i = 2; i < 5; i++) {
            int k = p + 8 * i;
            if (k < 34) {
                float inv = bb[(size_t)node * 20 + (k - 15)];
                s0e += inv * sWg[o0 * 34 + k];
                s1e += inv * sWg[(o0 + 1) * 34 + k];           // o0+1==15 row: zero pad
            }
        }
        s0e += __shfl_xor(s0e, 8, 64);
        s1e += __shfl_xor(s1e, 8, 64);
        s0e += __shfl_xor(s0e, 16, 64);
        s1e += __shfl_xor(s1e, 16, 64);
        s0e += __shfl_xor(s0e, 32, 64);
        s1e += __shfl_xor(s1e, 32, 64);
        if (p == 0)
            ((unsigned*)h_out)[(size_t)node * 8 + c2e] = pkh(s0e * dn, s1e * dn);
    } else {
        float c = 0.0f;
        if (lane < 8) c = avx * sW3[2 * pr] + avy * sW3[2 * pr + 1];   // sW3[15]==0
        c += __shfl_xor(c, 1, 64);
        c += __shfl_xor(c, 2, 64);
        c += __shfl_xor(c, 4, 64);        // lane 0 now holds the node sum
        if (lane == 0) ws2[wid] = c;
        __syncthreads();
        if (t == 0) {
            float s = 0.0f;
#pragma unroll
            for (int k = 0; k < 16; k++) s += ws2[k];
            atomicAdd(&bins[blockIdx.x & 63], s);
        }
    }
}

__global__ void k_finalize(const float* __restrict__ bins, const float* __restrict__ b3,
                           float* __restrict__ out) {
    float s = 0.0f;
    for (int k = 0; k < 64; k++) s += bins[k];
    out[0] = tanhf(s * (1.0f / (float)N_NODES) + b3[0]);
}

// ---------------------------------------------------------------------------
extern "C" void kernel_launch(void* const* d_in, const int* in_sizes, int n_in,
                              void* d_out, int out_size, void* d_ws, size_t ws_size,
                              hipStream_t stream) {
    const float* x1 = (const float*)d_in[0];
    const float* x2 = (const float*)d_in[1];
    const int* edges = (const int*)d_in[2];
    const float* W1 = (const float*)d_in[3];
    const float* b1 = (const float*)d_in[4];
    const float* Wg = (const float*)d_in[5];
    const float* bg = (const float*)d_in[6];
    const float* W3 = (const float*)d_in[7];
    const float* b3 = (const float*)d_in[8];
    const float* W4 = (const float*)d_in[9];
    const float* b4 = (const float*)d_in[10];

    const int* row = edges;             // edges[0]
    const int* col = edges + N_EDGES;   // edges[1]

    // workspace layout — ~30 MB (h0/h1 fp16: 3.2 MB each).
    char* ws = (char*)d_ws;
    unsigned* csr  = (unsigned*)ws;                              // NBKT*CAPB  (14.81 MB)
    float*    bb   = (float*)(csr + (size_t)NBKT * CAPB);        // N*20 f32   (8.0 MB)
    __half*   h0   = (__half*)(bb + (size_t)N_NODES * 20);       // N*16 fp16  (3.2 MB)
    __half*   h1   = h0 + (size_t)N_NODES * 16;                  // N*16 fp16  (3.2 MB)
    float*    dinv = (float*)(h1 + (size_t)N_NODES * 16);        // N
    int*      rs   = (int*)(dinv + N_NODES);                     // N
    int*      re   = rs + N_NODES;                               // N
    int*      gcur = re + N_NODES;                               // NBKT
    float*    bins = (float*)(gcur + NBKT);                      // 64

    int gN = (N_NODES + 255) / 256;                              // 391

    k_initg<<<1, 512, 0, stream>>>(gcur, bins);
    k_bucket<<<GEB, 512, 0, stream>>>(row, col, gcur, csr);
    k_sort<<<NBKT, 1024, 0, stream>>>(gcur, csr, rs, re, dinv);
    k_ab_h<<<gN, 256, 0, stream>>>(x1, x2, W1, b1, W4, b4, Wg, W3, dinv, bb, h0, bins);
    for (int t = 0; t < 5; t++) {
        const __half* hi = (t & 1) ? h1 : h0;
        __half* ho = (t & 1) ? h0 : h1;
        k_gather<<<N_NODES / 16, 1024, 0, stream>>>(rs, re, csr, hi, dinv, bb, Wg, bg, W3,
                                                    ho, bins, t == 4 ? 1 : 0);
    }
    k_finalize<<<1, 1, 0, stream>>>(bins, b3, (float*)d_out);
}

// Round 7
// 351.627 us; speedup vs baseline: 1.1387x; 1.1387x over previous
//
#include <hip/hip_runtime.h>
#include <hip/hip_fp16.h>
#include <math.h>

#define N_NODES 100000
#define N_BASE  5000
#define N_EDGES 3200000
#define NBKT    391       // dest buckets of 256 nodes
#define CAPB    9472      // csr slots per bucket (mean 8184, sigma 90 -> +14 sigma)
#define EPB     4096      // edges per k_bucket block
#define GEB     782       // ceil(N_EDGES / EPB)

__device__ inline unsigned pkh(float a, float b) {
    return (unsigned)__half_as_ushort(__float2half_rn(a)) |
           ((unsigned)__half_as_ushort(__float2half_rn(b)) << 16);
}

__device__ inline unsigned hadd2u(unsigned a, unsigned b) {
    __half2 r = __hadd2(*(__half2*)&a, *(__half2*)&b);
    return *(unsigned*)&r;
}

// ---------------------------------------------------------------------------
// k_initg: gcur[b] = b*CAPB, bins = 0
// ---------------------------------------------------------------------------
__global__ __launch_bounds__(512) void k_initg(int* __restrict__ gcur, float* __restrict__ bins) {
    int t = threadIdx.x;
    if (t < NBKT) gcur[t] = t * CAPB;
    if (t < 64) bins[t] = 0.0f;
}

// ---------------------------------------------------------------------------
// k_bucket: 782 blocks x 4096 edges x 512 threads; LDS position-sort then
// run-linear global writes (round-5 verified).
// ---------------------------------------------------------------------------
__global__ __launch_bounds__(512) void k_bucket(const int* __restrict__ row, const int* __restrict__ col,
                                                int* __restrict__ gcur, unsigned* __restrict__ csr) {
    __shared__ int hist[NBKT], gbase[NBKT], curi[NBKT], excl[NBKT];
    __shared__ int sc[512];
    __shared__ unsigned sdst[EPB];     // packed (d&255)<<17 | src, sorted by bucket
    __shared__ int sadr[EPB];          // final global csr address per slot
    int t = threadIdx.x;
    int e0 = blockIdx.x * EPB;
    int cnt = (N_EDGES - e0 < EPB) ? (N_EDGES - e0) : EPB;
    for (int k = t; k < NBKT; k += 512) hist[k] = 0;
    __syncthreads();
    for (int j = t; j < cnt; j += 512) atomicAdd(&hist[col[e0 + j] >> 8], 1);
    __syncthreads();
    sc[t] = (t < NBKT) ? hist[t] : 0;
    __syncthreads();
    for (int off = 1; off < 512; off <<= 1) {
        int v = (t >= off) ? sc[t - off] : 0;
        __syncthreads();
        sc[t] += v;
        __syncthreads();
    }
    if (t < NBKT) {
        int e = sc[t] - hist[t];
        excl[t] = e;
        curi[t] = e;
        gbase[t] = (hist[t] > 0) ? atomicAdd(&gcur[t], hist[t]) : 0;
    }
    __syncthreads();
    for (int j = t; j < cnt; j += 512) {
        int d = col[e0 + j];           // L2-warm re-read
        int s = row[e0 + j];
        int b = d >> 8;
        int pos = atomicAdd(&curi[b], 1);              // pos in [excl[b], excl[b]+hist[b])
        sdst[pos] = ((unsigned)(d & 255) << 17) | (unsigned)s;
        sadr[pos] = gbase[b] + (pos - excl[b]);
    }
    __syncthreads();
    for (int j = t; j < cnt; j += 512) csr[sadr[j]] = sdst[j];   // run-linear writes
}

// ---------------------------------------------------------------------------
// k_sort: one block per bucket, 1024 threads; LDS counting sort (verified).
// ---------------------------------------------------------------------------
__global__ __launch_bounds__(1024) void k_sort(const int* __restrict__ gcur, unsigned* __restrict__ csr,
                                               int* __restrict__ rs, int* __restrict__ re,
                                               float* __restrict__ dinv) {
    __shared__ unsigned stage[CAPB];
    __shared__ int hist[256], offs[256], cur[256];
    int t = threadIdx.x, b = blockIdx.x;
    int base = b * CAPB;
    int cnt = gcur[b] - base;
    if (t < 256) hist[t] = 0;
    for (int j = t; j < cnt; j += 1024) stage[j] = csr[base + j];
    __syncthreads();
    for (int j = t; j < cnt; j += 1024) atomicAdd(&hist[stage[j] >> 17], 1);
    __syncthreads();
    if (t < 256) offs[t] = hist[t];
    __syncthreads();
    for (int off = 1; off < 256; off <<= 1) {
        int v = 0;
        if (t < 256 && t >= off) v = offs[t - off];
        __syncthreads();
        if (t < 256) offs[t] += v;
        __syncthreads();
    }
    if (t < 256) {
        int excl = offs[t] - hist[t];
        cur[t] = excl;
        int node = b * 256 + t;
        if (node < N_NODES) {
            rs[node] = base + excl;
            re[node] = base + excl + hist[t];
            dinv[node] = rsqrtf((float)(hist[t] + 1));   // +1 self loop
        }
    }
    __syncthreads();
    for (int j = t; j < cnt; j += 1024) {
        unsigned p = stage[j];
        int slot = atomicAdd(&cur[p >> 17], 1);
        csr[base + slot] = p & 0x1FFFFu;             // pure src
    }
}

// ---------------------------------------------------------------------------
// k_ab_h: bb = [x1 | tile(x2)] @ W4^T + b4  (float4 stores, f32)
//         h0 = dinv * (Wg @ [relu(x1@W1^T+b1) | bb])   (fp16 stores)
//         bins += W3[15:34].bb   (iteration-invariant output part)
// ---------------------------------------------------------------------------
__global__ __launch_bounds__(256) void k_ab_h(const float* __restrict__ x1, const float* __restrict__ x2,
                                              const float* __restrict__ W1, const float* __restrict__ b1,
                                              const float* __restrict__ W4, const float* __restrict__ b4,
                                              const float* __restrict__ Wg, const float* __restrict__ W3,
                                              const float* __restrict__ dinv,
                                              float* __restrict__ bb, __half* __restrict__ h0,
                                              float* __restrict__ bins) {
    __shared__ float sW1[225], sb1[15], sW4[361], sb4[19], sWg[510], sW3b[19];
    for (int t = threadIdx.x; t < 225; t += 256) sW1[t] = W1[t];
    for (int t = threadIdx.x; t < 361; t += 256) sW4[t] = W4[t];
    for (int t = threadIdx.x; t < 510; t += 256) sWg[t] = Wg[t];
    if (threadIdx.x < 15) sb1[threadIdx.x] = b1[threadIdx.x];
    if (threadIdx.x < 19) { sb4[threadIdx.x] = b4[threadIdx.x]; sW3b[threadIdx.x] = W3[15 + threadIdx.x]; }
    __syncthreads();
    int i = blockIdx.x * 256 + threadIdx.x;
    bool valid = i < N_NODES;
    int ii = valid ? i : 0;
    float x[15];
#pragma unroll
    for (int k = 0; k < 15; k++) x[k] = x1[(size_t)ii * 15 + k];
    float xt[4];
    int ib = ii % N_BASE;
#pragma unroll
    for (int k = 0; k < 4; k++) xt[k] = x2[(size_t)ib * 4 + k];
    float in[34];
    float bp = 0.0f;
#pragma unroll
    for (int o = 0; o < 19; o++) {
        float s = sb4[o];
#pragma unroll
        for (int k = 0; k < 15; k++) s += x[k] * sW4[o * 19 + k];
#pragma unroll
        for (int k = 0; k < 4; k++) s += xt[k] * sW4[o * 19 + 15 + k];
        in[15 + o] = s;
        bp += s * sW3b[o];
    }
#pragma unroll
    for (int o = 0; o < 15; o++) {
        float s = sb1[o];
#pragma unroll
        for (int k = 0; k < 15; k++) s += x[k] * sW1[o * 15 + k];
        in[o] = fmaxf(s, 0.0f);
    }
    float dn = dinv[ii];
    if (valid) {
        float4* bbp = (float4*)(bb + (size_t)ii * 20);
        bbp[0] = make_float4(in[15], in[16], in[17], in[18]);
        bbp[1] = make_float4(in[19], in[20], in[21], in[22]);
        bbp[2] = make_float4(in[23], in[24], in[25], in[26]);
        bbp[3] = make_float4(in[27], in[28], in[29], in[30]);
        bbp[4] = make_float4(in[31], in[32], in[33], 0.0f);   // [19] pad, never consumed
        float hv[15];
#pragma unroll
        for (int o = 0; o < 15; o++) {
            float s = 0.0f;
#pragma unroll
            for (int k = 0; k < 34; k++) s += in[k] * sWg[o * 34 + k];
            hv[o] = s * dn;
        }
        unsigned hu[8];
#pragma unroll
        for (int k = 0; k < 7; k++) hu[k] = pkh(hv[2 * k], hv[2 * k + 1]);
        hu[7] = pkh(hv[14], 0.0f);                            // ch 15 pad, always 0
        uint4* hp = (uint4*)(h0 + (size_t)ii * 16);
        hp[0] = make_uint4(hu[0], hu[1], hu[2], hu[3]);
        hp[1] = make_uint4(hu[4], hu[5], hu[6], hu[7]);
    }
    float val = valid ? bp : 0.0f;
#pragma unroll
    for (int off = 32; off > 0; off >>= 1) val += __shfl_down(val, off, 64);
    __shared__ float wsum[4];
    if ((threadIdx.x & 63) == 0) wsum[threadIdx.x >> 6] = val;
    __syncthreads();
    if (threadIdx.x == 0) atomicAdd(&bins[blockIdx.x & 63], wsum[0] + wsum[1] + wsum[2] + wsum[3]);
}

// ---------------------------------------------------------------------------
// k_gather (round 7): TWO nodes per wave to double per-wave MLP (evidence:
// time invariant under instruction reduction, so latency x outstanding-loads
// is the bound). Per 32-edge batch per node: one combined csr load (lanes
// 0-31 node0, 32-63 node1) + two INDEPENDENT dwordx4 gather streams.
// fp16 pk_add accumulation + round-6-verified reduce-scatter (pr mapping).
// Epilogue is now LDS/barrier-free: after the allreduce over lane bits 3..5,
// channel pair j is held by every lane whose low-3 bits == rev3(j), so
// in[k<15] comes from 4 shfls + parity select (round-4-verified pattern).
// Waves retire independently (no block sync except the last-iter reduction).
// ---------------------------------------------------------------------------
__global__ __launch_bounds__(1024) void k_gather(const int* __restrict__ rs, const int* __restrict__ re,
                                                 const unsigned* __restrict__ csr,
                                                 const __half* __restrict__ h_in,
                                                 const float* __restrict__ dinv,
                                                 const float* __restrict__ bb,
                                                 const float* __restrict__ Wg,
                                                 const float* __restrict__ bg,
                                                 const float* __restrict__ W3,
                                                 __half* __restrict__ h_out,
                                                 float* __restrict__ bins, int last) {
    __shared__ float sWg[544], sbg[16], sW3[16];
    __shared__ float ws2[16];
    int t = threadIdx.x;
    for (int k = t; k < 544; k += 1024) sWg[k] = (k < 510) ? Wg[k] : 0.0f;
    if (t < 16) { sbg[t] = (t < 15) ? bg[t] : 0.0f; sW3[t] = (t < 15) ? W3[t] : 0.0f; }
    __syncthreads();
    int wid = t >> 6;
    int n0 = blockIdx.x * 32 + wid * 2;
    int n1 = n0 + 1;
    int lane = t & 63, es = lane >> 1, half = lane & 1;
    int rs0 = rs[n0], deg0 = re[n0] - rs0;
    int rs1 = rs[n1], deg1 = re[n1] - rs1;
    const uint4* hp4 = (const uint4*)h_in;                 // one row = 2 uint4 (32B)
    // self rows: node0 on es==0 lanes, node1 on es==1 lanes (each counted once)
    uint4 s0v = make_uint4(0u, 0u, 0u, 0u), s1v = make_uint4(0u, 0u, 0u, 0u);
    if (es == 0) s0v = hp4[(size_t)n0 * 2 + half];
    if (es == 1) s1v = hp4[(size_t)n1 * 2 + half];
    unsigned a00 = s0v.x, a01 = s0v.y, a02 = s0v.z, a03 = s0v.w;
    unsigned a10 = s1v.x, a11 = s1v.y, a12 = s1v.z, a13 = s1v.w;
    int degm = deg0 > deg1 ? deg0 : deg1;
    for (int base = 0; base < degm; base += 32) {
        // combined csr load: lanes 0-31 -> node0 edges, lanes 32-63 -> node1
        int le = lane & 31;
        bool hi = lane >= 32;
        int src = hi ? rs1 : rs0;
        int dg = hi ? deg1 : deg0;
        unsigned ce = 0;
        if (base + le < dg) ce = csr[src + base + le];
        int lim0 = deg0 - base;                            // wave-uniform
        int lim1 = deg1 - base;
        unsigned pa = __shfl(ce, es, 64);                  // node0 edge es
        unsigned pb = __shfl(ce, 32 + es, 64);             // node1 edge es
        uint4 va = make_uint4(0u, 0u, 0u, 0u);
        uint4 vb = make_uint4(0u, 0u, 0u, 0u);
        if (es < lim0) va = hp4[(size_t)pa * 2 + half];
        if (es < lim1) vb = hp4[(size_t)pb * 2 + half];
        a00 = hadd2u(a00, va.x); a01 = hadd2u(a01, va.y);
        a02 = hadd2u(a02, va.z); a03 = hadd2u(a03, va.w);
        a10 = hadd2u(a10, vb.x); a11 = hadd2u(a11, vb.y);
        a12 = hadd2u(a12, vb.z); a13 = hadd2u(a13, vb.w);
    }
    // reduce-scatter over lane bits 1..5 (round-6-verified), per node.
    int sel2 = (lane >> 1) & 1;
    int sel4 = (lane >> 2) & 1;
    unsigned kk0, kk1;
    {
        unsigned sA = sel2 ? a00 : a02, sB = sel2 ? a01 : a03;
        unsigned kA = sel2 ? a02 : a00, kB = sel2 ? a03 : a01;
        kA = hadd2u(kA, __shfl_xor(sA, 2, 64));
        kB = hadd2u(kB, __shfl_xor(sB, 2, 64));
        unsigned sd = sel4 ? kA : kB, kc = sel4 ? kB : kA;
        kc = hadd2u(kc, __shfl_xor(sd, 4, 64));
        kc = hadd2u(kc, __shfl_xor(kc, 8, 64));
        kc = hadd2u(kc, __shfl_xor(kc, 16, 64));
        kc = hadd2u(kc, __shfl_xor(kc, 32, 64));
        kk0 = kc;
    }
    {
        unsigned sA = sel2 ? a10 : a12, sB = sel2 ? a11 : a13;
        unsigned kA = sel2 ? a12 : a10, kB = sel2 ? a13 : a11;
        kA = hadd2u(kA, __shfl_xor(sA, 2, 64));
        kB = hadd2u(kB, __shfl_xor(sB, 2, 64));
        unsigned sd = sel4 ? kA : kB, kc = sel4 ? kB : kA;
        kc = hadd2u(kc, __shfl_xor(sd, 4, 64));
        kc = hadd2u(kc, __shfl_xor(kc, 8, 64));
        kc = hadd2u(kc, __shfl_xor(kc, 16, 64));
        kc = hadd2u(kc, __shfl_xor(kc, 32, 64));
        kk1 = kc;
    }
    int pr = 4 * half + 2 * sel2 + sel4;   // lane's dword(pair) index; low-3-bit bijection
    float dn0 = dinv[n0], dn1 = dinv[n1];
    float2 f0 = __half22float2(*(__half2*)&kk0);
    float2 f1 = __half22float2(*(__half2*)&kk1);
    float avx0 = fmaxf(dn0 * f0.x + sbg[2 * pr], 0.0f);
    float avy0 = fmaxf(dn0 * f0.y + sbg[2 * pr + 1], 0.0f);   // pr==7 -> ch15 = 0
    float avx1 = fmaxf(dn1 * f1.x + sbg[2 * pr], 0.0f);
    float avy1 = fmaxf(dn1 * f1.y + sbg[2 * pr + 1], 0.0f);
    if (!last) {
        int p = lane >> 3, c2e = lane & 7, o0 = 2 * c2e;
        // pair j is on lanes with low3 == rev3(j)
        int j0 = p >> 1, j1 = (p + 8) >> 1;
        int l0 = ((j0 & 1) << 2) | (j0 & 2) | ((j0 >> 2) & 1);
        int l1 = ((j1 & 1) << 2) | (j1 & 2) | ((j1 >> 2) & 1);
        float ex0a = __shfl(avx0, l0, 64), ey0a = __shfl(avy0, l0, 64);
        float ex1a = __shfl(avx0, l1, 64), ey1a = __shfl(avy0, l1, 64);
        float ex0b = __shfl(avx1, l0, 64), ey0b = __shfl(avy1, l0, 64);
        float ex1b = __shfl(avx1, l1, 64), ey1b = __shfl(avy1, l1, 64);
        float inv0a = (p & 1) ? ey0a : ex0a;
        float inv1a = (p & 1) ? ey1a : ex1a;
        float inv0b = (p & 1) ? ey0b : ex0b;
        float inv1b = (p & 1) ? ey1b : ex1b;
        if (p == 7) { inv1a = bb[(size_t)n0 * 20 + 0]; inv1b = bb[(size_t)n1 * 20 + 0]; }
        float wq0 = sWg[o0 * 34 + p],       wq1 = sWg[o0 * 34 + p + 8];
        float wr0 = sWg[(o0 + 1) * 34 + p], wr1 = sWg[(o0 + 1) * 34 + p + 8];
        float s0a = inv0a * wq0 + inv1a * wq1;
        float s1a = inv0a * wr0 + inv1a * wr1;
        float s0b = inv0b * wq0 + inv1b * wq1;
        float s1b = inv0b * wr0 + inv1b * wr1;
#pragma unroll
        for (int i = 2; i < 5; i++) {
            int k = p + 8 * i;
            if (k < 34) {
                float ia = bb[(size_t)n0 * 20 + (k - 15)];
                float ib2 = bb[(size_t)n1 * 20 + (k - 15)];
                float w0 = sWg[o0 * 34 + k], w1 = sWg[(o0 + 1) * 34 + k];
                s0a += ia * w0; s1a += ia * w1;
                s0b += ib2 * w0; s1b += ib2 * w1;
            }
        }
        s0a += __shfl_xor(s0a, 8, 64);  s1a += __shfl_xor(s1a, 8, 64);
        s0a += __shfl_xor(s0a, 16, 64); s1a += __shfl_xor(s1a, 16, 64);
        s0a += __shfl_xor(s0a, 32, 64); s1a += __shfl_xor(s1a, 32, 64);
        s0b += __shfl_xor(s0b, 8, 64);  s1b += __shfl_xor(s1b, 8, 64);
        s0b += __shfl_xor(s0b, 16, 64); s1b += __shfl_xor(s1b, 16, 64);
        s0b += __shfl_xor(s0b, 32, 64); s1b += __shfl_xor(s1b, 32, 64);
        if (p == 0) {
            ((unsigned*)h_out)[(size_t)n0 * 8 + c2e] = pkh(s0a * dn0, s1a * dn0);
            ((unsigned*)h_out)[(size_t)n1 * 8 + c2e] = pkh(s0b * dn1, s1b * dn1);
        }
    } else {
        float c = 0.0f;
        if (lane < 8) {
            c = avx0 * sW3[2 * pr] + avy0 * sW3[2 * pr + 1]
              + avx1 * sW3[2 * pr] + avy1 * sW3[2 * pr + 1];   // sW3[15]==0
        }
        c += __shfl_xor(c, 1, 64);
        c += __shfl_xor(c, 2, 64);
        c += __shfl_xor(c, 4, 64);        // lane 0 holds both nodes' sum
        if (lane == 0) ws2[wid] = c;
        __syncthreads();
        if (t == 0) {
            float s = 0.0f;
#pragma unroll
            for (int k = 0; k < 16; k++) s += ws2[k];
            atomicAdd(&bins[blockIdx.x & 63], s);
        }
    }
}

__global__ void k_finalize(const float* __restrict__ bins, const float* __restrict__ b3,
                           float* __restrict__ out) {
    float s = 0.0f;
    for (int k = 0; k < 64; k++) s += bins[k];
    out[0] = tanhf(s * (1.0f / (float)N_NODES) + b3[0]);
}

// ---------------------------------------------------------------------------
extern "C" void kernel_launch(void* const* d_in, const int* in_sizes, int n_in,
                              void* d_out, int out_size, void* d_ws, size_t ws_size,
                              hipStream_t stream) {
    const float* x1 = (const float*)d_in[0];
    const float* x2 = (const float*)d_in[1];
    const int* edges = (const int*)d_in[2];
    const float* W1 = (const float*)d_in[3];
    const float* b1 = (const float*)d_in[4];
    const float* Wg = (const float*)d_in[5];
    const float* bg = (const float*)d_in[6];
    const float* W3 = (const float*)d_in[7];
    const float* b3 = (const float*)d_in[8];
    const float* W4 = (const float*)d_in[9];
    const float* b4 = (const float*)d_in[10];

    const int* row = edges;             // edges[0]
    const int* col = edges + N_EDGES;   // edges[1]

    // workspace layout — ~30 MB (h0/h1 fp16: 3.2 MB each).
    char* ws = (char*)d_ws;
    unsigned* csr  = (unsigned*)ws;                              // NBKT*CAPB  (14.81 MB)
    float*    bb   = (float*)(csr + (size_t)NBKT * CAPB);        // N*20 f32   (8.0 MB)
    __half*   h0   = (__half*)(bb + (size_t)N_NODES * 20);       // N*16 fp16  (3.2 MB)
    __half*   h1   = h0 + (size_t)N_NODES * 16;                  // N*16 fp16  (3.2 MB)
    float*    dinv = (float*)(h1 + (size_t)N_NODES * 16);        // N
    int*      rs   = (int*)(dinv + N_NODES);                     // N
    int*      re   = rs + N_NODES;                               // N
    int*      gcur = re + N_NODES;                               // NBKT
    float*    bins = (float*)(gcur + NBKT);                      // 64

    int gN = (N_NODES + 255) / 256;                              // 391

    k_initg<<<1, 512, 0, stream>>>(gcur, bins);
    k_bucket<<<GEB, 512, 0, stream>>>(row, col, gcur, csr);
    k_sort<<<NBKT, 1024, 0, stream>>>(gcur, csr, rs, re, dinv);
    k_ab_h<<<gN, 256, 0, stream>>>(x1, x2, W1, b1, W4, b4, Wg, W3, dinv, bb, h0, bins);
    for (int t = 0; t < 5; t++) {
        const __half* hi = (t & 1) ? h1 : h0;
        __half* ho = (t & 1) ? h0 : h1;
        k_gather<<<N_NODES / 32, 1024, 0, stream>>>(rs, re, csr, hi, dinv, bb, Wg, bg, W3,
                                                    ho, bins, t == 4 ? 1 : 0);
    }
    k_finalize<<<1, 1, 0, stream>>>(bins, b3, (float*)d_out);
}

// Round 9
// 344.791 us; speedup vs baseline: 1.1613x; 1.0198x over previous
//
#include <hip/hip_runtime.h>
#include <hip/hip_fp16.h>
#include <math.h>

#define N_NODES 100000
#define N_BASE  5000
#define N_EDGES 3200000
#define NBKT    391       // dest buckets of 256 nodes
#define CAPB    9472      // csr slots per bucket (mean 8184, sigma 90 -> +14 sigma)
#define EPB     4096      // edges per k_bucket block
#define GEB     782       // ceil(N_EDGES / EPB)

__device__ inline unsigned pkh(float a, float b) {
    return (unsigned)__half_as_ushort(__float2half_rn(a)) |
           ((unsigned)__half_as_ushort(__float2half_rn(b)) << 16);
}

__device__ inline unsigned hadd2u(unsigned a, unsigned b) {
    __half2 r = __hadd2(*(__half2*)&a, *(__half2*)&b);
    return *(unsigned*)&r;
}

// ---------------------------------------------------------------------------
// k_initg: gcur[b] = b*CAPB, bins = 0
// ---------------------------------------------------------------------------
__global__ __launch_bounds__(512) void k_initg(int* __restrict__ gcur, float* __restrict__ bins) {
    int t = threadIdx.x;
    if (t < NBKT) gcur[t] = t * CAPB;
    if (t < 64) bins[t] = 0.0f;
}

// ---------------------------------------------------------------------------
// k_bucket: 782 blocks x 4096 edges x 512 threads; LDS position-sort then
// run-linear global writes (round-5 verified).
// ---------------------------------------------------------------------------
__global__ __launch_bounds__(512) void k_bucket(const int* __restrict__ row, const int* __restrict__ col,
                                                int* __restrict__ gcur, unsigned* __restrict__ csr) {
    __shared__ int hist[NBKT], gbase[NBKT], curi[NBKT], excl[NBKT];
    __shared__ int sc[512];
    __shared__ unsigned sdst[EPB];     // packed (d&255)<<17 | src, sorted by bucket
    __shared__ int sadr[EPB];          // final global csr address per slot
    int t = threadIdx.x;
    int e0 = blockIdx.x * EPB;
    int cnt = (N_EDGES - e0 < EPB) ? (N_EDGES - e0) : EPB;
    for (int k = t; k < NBKT; k += 512) hist[k] = 0;
    __syncthreads();
    for (int j = t; j < cnt; j += 512) atomicAdd(&hist[col[e0 + j] >> 8], 1);
    __syncthreads();
    sc[t] = (t < NBKT) ? hist[t] : 0;
    __syncthreads();
    for (int off = 1; off < 512; off <<= 1) {
        int v = (t >= off) ? sc[t - off] : 0;
        __syncthreads();
        sc[t] += v;
        __syncthreads();
    }
    if (t < NBKT) {
        int e = sc[t] - hist[t];
        excl[t] = e;
        curi[t] = e;
        gbase[t] = (hist[t] > 0) ? atomicAdd(&gcur[t], hist[t]) : 0;
    }
    __syncthreads();
    for (int j = t; j < cnt; j += 512) {
        int d = col[e0 + j];           // L2-warm re-read
        int s = row[e0 + j];
        int b = d >> 8;
        int pos = atomicAdd(&curi[b], 1);              // pos in [excl[b], excl[b]+hist[b])
        sdst[pos] = ((unsigned)(d & 255) << 17) | (unsigned)s;
        sadr[pos] = gbase[b] + (pos - excl[b]);
    }
    __syncthreads();
    for (int j = t; j < cnt; j += 512) csr[sadr[j]] = sdst[j];   // run-linear writes
}

// ---------------------------------------------------------------------------
// k_sort: one block per bucket, 1024 threads; LDS counting sort (verified).
// ---------------------------------------------------------------------------
__global__ __launch_bounds__(1024) void k_sort(const int* __restrict__ gcur, unsigned* __restrict__ csr,
                                               int* __restrict__ rs, int* __restrict__ re,
                                               float* __restrict__ dinv) {
    __shared__ unsigned stage[CAPB];
    __shared__ int hist[256], offs[256], cur[256];
    int t = threadIdx.x, b = blockIdx.x;
    int base = b * CAPB;
    int cnt = gcur[b] - base;
    if (t < 256) hist[t] = 0;
    for (int j = t; j < cnt; j += 1024) stage[j] = csr[base + j];
    __syncthreads();
    for (int j = t; j < cnt; j += 1024) atomicAdd(&hist[stage[j] >> 17], 1);
    __syncthreads();
    if (t < 256) offs[t] = hist[t];
    __syncthreads();
    for (int off = 1; off < 256; off <<= 1) {
        int v = 0;
        if (t < 256 && t >= off) v = offs[t - off];
        __syncthreads();
        if (t < 256) offs[t] += v;
        __syncthreads();
    }
    if (t < 256) {
        int excl = offs[t] - hist[t];
        cur[t] = excl;
        int node = b * 256 + t;
        if (node < N_NODES) {
            rs[node] = base + excl;
            re[node] = base + excl + hist[t];
            dinv[node] = rsqrtf((float)(hist[t] + 1));   // +1 self loop
        }
    }
    __syncthreads();
    for (int j = t; j < cnt; j += 1024) {
        unsigned p = stage[j];
        int slot = atomicAdd(&cur[p >> 17], 1);
        csr[base + slot] = p & 0x1FFFFu;             // pure src
    }
}

// ---------------------------------------------------------------------------
// k_ab_h: bb = [x1 | tile(x2)] @ W4^T + b4  (float4 stores, f32)
//         h0 = dinv * (Wg @ [relu(x1@W1^T+b1) | bb])   (fp16 stores)
//         bins += W3[15:34].bb   (iteration-invariant output part)
// ---------------------------------------------------------------------------
__global__ __launch_bounds__(256) void k_ab_h(const float* __restrict__ x1, const float* __restrict__ x2,
                                              const float* __restrict__ W1, const float* __restrict__ b1,
                                              const float* __restrict__ W4, const float* __restrict__ b4,
                                              const float* __restrict__ Wg, const float* __restrict__ W3,
                                              const float* __restrict__ dinv,
                                              float* __restrict__ bb, __half* __restrict__ h0,
                                              float* __restrict__ bins) {
    __shared__ float sW1[225], sb1[15], sW4[361], sb4[19], sWg[510], sW3b[19];
    for (int t = threadIdx.x; t < 225; t += 256) sW1[t] = W1[t];
    for (int t = threadIdx.x; t < 361; t += 256) sW4[t] = W4[t];
    for (int t = threadIdx.x; t < 510; t += 256) sWg[t] = Wg[t];
    if (threadIdx.x < 15) sb1[threadIdx.x] = b1[threadIdx.x];
    if (threadIdx.x < 19) { sb4[threadIdx.x] = b4[threadIdx.x]; sW3b[threadIdx.x] = W3[15 + threadIdx.x]; }
    __syncthreads();
    int i = blockIdx.x * 256 + threadIdx.x;
    bool valid = i < N_NODES;
    int ii = valid ? i : 0;
    float x[15];
#pragma unroll
    for (int k = 0; k < 15; k++) x[k] = x1[(size_t)ii * 15 + k];
    float xt[4];
    int ib = ii % N_BASE;
#pragma unroll
    for (int k = 0; k < 4; k++) xt[k] = x2[(size_t)ib * 4 + k];
    float in[34];
    float bp = 0.0f;
#pragma unroll
    for (int o = 0; o < 19; o++) {
        float s = sb4[o];
#pragma unroll
        for (int k = 0; k < 15; k++) s += x[k] * sW4[o * 19 + k];
#pragma unroll
        for (int k = 0; k < 4; k++) s += xt[k] * sW4[o * 19 + 15 + k];
        in[15 + o] = s;
        bp += s * sW3b[o];
    }
#pragma unroll
    for (int o = 0; o < 15; o++) {
        float s = sb1[o];
#pragma unroll
        for (int k = 0; k < 15; k++) s += x[k] * sW1[o * 15 + k];
        in[o] = fmaxf(s, 0.0f);
    }
    float dn = dinv[ii];
    if (valid) {
        float4* bbp = (float4*)(bb + (size_t)ii * 20);
        bbp[0] = make_float4(in[15], in[16], in[17], in[18]);
        bbp[1] = make_float4(in[19], in[20], in[21], in[22]);
        bbp[2] = make_float4(in[23], in[24], in[25], in[26]);
        bbp[3] = make_float4(in[27], in[28], in[29], in[30]);
        bbp[4] = make_float4(in[31], in[32], in[33], 0.0f);   // [19] pad, never consumed
        float hv[15];
#pragma unroll
        for (int o = 0; o < 15; o++) {
            float s = 0.0f;
#pragma unroll
            for (int k = 0; k < 34; k++) s += in[k] * sWg[o * 34 + k];
            hv[o] = s * dn;
        }
        unsigned hu[8];
#pragma unroll
        for (int k = 0; k < 7; k++) hu[k] = pkh(hv[2 * k], hv[2 * k + 1]);
        hu[7] = pkh(hv[14], 0.0f);                            // ch 15 pad, always 0
        uint4* hp = (uint4*)(h0 + (size_t)ii * 16);
        hp[0] = make_uint4(hu[0], hu[1], hu[2], hu[3]);
        hp[1] = make_uint4(hu[4], hu[5], hu[6], hu[7]);
    }
    float val = valid ? bp : 0.0f;
#pragma unroll
    for (int off = 32; off > 0; off >>= 1) val += __shfl_down(val, off, 64);
    __shared__ float wsum[4];
    if ((threadIdx.x & 63) == 0) wsum[threadIdx.x >> 6] = val;
    __syncthreads();
    if (threadIdx.x == 0) atomicAdd(&bins[blockIdx.x & 63], wsum[0] + wsum[1] + wsum[2] + wsum[3]);
}

// ---------------------------------------------------------------------------
// k_gather (round 8, resubmitted after infra failure): 64-edge batches with
// LANE-OWNED edges. Each lane serves node g = lane>>5 and owns edges lg and
// lg+32 (lg = lane&31), loading the FULL 32B row per edge (2 x dwordx4, same
// 128B line). Per iteration: 2 predicated csr loads + 4 gathers, 128 edge
// slots -> virtually all waves (P(deg>64) ~ 1e-7) run ONE latency round
// (round 7: 71% of waves ran 2 serial rounds for max(deg0,deg1)>32).
// No shuffles in the gather loop. Reduce: per-lane over lg bits 0..4; lane
// keeps dword pr = 4*b0+2*b1+b2 (send-the-discard-half; 9 shfl + 9 hadd).
// Source lane for pair j is rev3(j) within the 32-lane group -- same formula
// as round 7's verified epilogue; node1 sources at 32+l.
// ---------------------------------------------------------------------------
__global__ __launch_bounds__(1024) void k_gather(const int* __restrict__ rs, const int* __restrict__ re,
                                                 const unsigned* __restrict__ csr,
                                                 const __half* __restrict__ h_in,
                                                 const float* __restrict__ dinv,
                                                 const float* __restrict__ bb,
                                                 const float* __restrict__ Wg,
                                                 const float* __restrict__ bg,
                                                 const float* __restrict__ W3,
                                                 __half* __restrict__ h_out,
                                                 float* __restrict__ bins, int last) {
    __shared__ float sWg[544], sbg[16], sW3[16];
    __shared__ float ws2[16];
    int t = threadIdx.x;
    for (int k = t; k < 544; k += 1024) sWg[k] = (k < 510) ? Wg[k] : 0.0f;
    if (t < 16) { sbg[t] = (t < 15) ? bg[t] : 0.0f; sW3[t] = (t < 15) ? W3[t] : 0.0f; }
    __syncthreads();
    int wid = t >> 6;
    int n0 = blockIdx.x * 32 + wid * 2;
    int lane = t & 63, g = lane >> 5, lg = lane & 31;
    int ng = n0 + g;
    int rsg = rs[ng];
    int degg = re[ng] - rsg;
    int dego = __shfl_xor(degg, 32, 64);
    int degm = degg > dego ? degg : dego;                  // wave-uniform bound
    const uint4* hp4 = (const uint4*)h_in;                 // one row = 2 uint4 (32B)
    // self row: full row on the lg==0 lane of each group (counted exactly once)
    uint4 sL = make_uint4(0u, 0u, 0u, 0u), sH = make_uint4(0u, 0u, 0u, 0u);
    if (lg == 0) { sL = hp4[(size_t)ng * 2]; sH = hp4[(size_t)ng * 2 + 1]; }
    unsigned a0 = sL.x, a1 = sL.y, a2 = sL.z, a3 = sL.w;
    unsigned a4 = sH.x, a5 = sH.y, a6 = sH.z, a7 = sH.w;
    for (int base = 0; base < degm; base += 64) {
        bool vA = base + lg < degg;
        bool vB = base + 32 + lg < degg;
        unsigned pa = 0u, pb = 0u;
        if (vA) pa = csr[rsg + base + lg];
        if (vB) pb = csr[rsg + base + 32 + lg];
        uint4 vaL = make_uint4(0u, 0u, 0u, 0u), vaH = make_uint4(0u, 0u, 0u, 0u);
        uint4 vbL = make_uint4(0u, 0u, 0u, 0u), vbH = make_uint4(0u, 0u, 0u, 0u);
        if (vA) { vaL = hp4[(size_t)pa * 2]; vaH = hp4[(size_t)pa * 2 + 1]; }
        if (vB) { vbL = hp4[(size_t)pb * 2]; vbH = hp4[(size_t)pb * 2 + 1]; }
        a0 = hadd2u(a0, vaL.x); a1 = hadd2u(a1, vaL.y);
        a2 = hadd2u(a2, vaL.z); a3 = hadd2u(a3, vaL.w);
        a4 = hadd2u(a4, vaH.x); a5 = hadd2u(a5, vaH.y);
        a6 = hadd2u(a6, vaH.z); a7 = hadd2u(a7, vaH.w);
        a0 = hadd2u(a0, vbL.x); a1 = hadd2u(a1, vbL.y);
        a2 = hadd2u(a2, vbL.z); a3 = hadd2u(a3, vbL.w);
        a4 = hadd2u(a4, vbH.x); a5 = hadd2u(a5, vbH.y);
        a6 = hadd2u(a6, vbH.z); a7 = hadd2u(a7, vbH.w);
    }
    // per-lane reduce over lg bits 0..4 (send-the-discard-half); lane ends
    // holding row dword pr = 4*b0 + 2*b1 + b2 of its node's sum.
    int b0 = lg & 1, b1 = (lg >> 1) & 1, b2 = (lg >> 2) & 1;
    unsigned kA0 = b0 ? a4 : a0, kA1 = b0 ? a5 : a1, kA2 = b0 ? a6 : a2, kA3 = b0 ? a7 : a3;
    unsigned sA0 = b0 ? a0 : a4, sA1 = b0 ? a1 : a5, sA2 = b0 ? a2 : a6, sA3 = b0 ? a3 : a7;
    kA0 = hadd2u(kA0, __shfl_xor(sA0, 1, 64));
    kA1 = hadd2u(kA1, __shfl_xor(sA1, 1, 64));
    kA2 = hadd2u(kA2, __shfl_xor(sA2, 1, 64));
    kA3 = hadd2u(kA3, __shfl_xor(sA3, 1, 64));
    unsigned kB0 = b1 ? kA2 : kA0, kB1 = b1 ? kA3 : kA1;
    unsigned sB0 = b1 ? kA0 : kA2, sB1 = b1 ? kA1 : kA3;
    kB0 = hadd2u(kB0, __shfl_xor(sB0, 2, 64));
    kB1 = hadd2u(kB1, __shfl_xor(sB1, 2, 64));
    unsigned kk = b2 ? kB1 : kB0;
    unsigned sd = b2 ? kB0 : kB1;
    kk = hadd2u(kk, __shfl_xor(sd, 4, 64));
    kk = hadd2u(kk, __shfl_xor(kk, 8, 64));
    kk = hadd2u(kk, __shfl_xor(kk, 16, 64));
    int pr = 4 * b0 + 2 * b1 + b2;
    float dng = dinv[ng];
    float2 f = __half22float2(*(__half2*)&kk);
    float avx = fmaxf(dng * f.x + sbg[2 * pr], 0.0f);
    float avy = fmaxf(dng * f.y + sbg[2 * pr + 1], 0.0f);   // pr==7 -> ch15 = 0
    if (!last) {
        int n1 = n0 + 1;
        float dn0 = __shfl(dng, 0, 64), dn1 = __shfl(dng, 32, 64);
        int p = lane >> 3, c2e = lane & 7, o0 = 2 * c2e;
        // pair j of node g lives on lane 32*g + rev3(j)
        int j0 = p >> 1, j1 = (p + 8) >> 1;
        int l0 = ((j0 & 1) << 2) | (j0 & 2) | ((j0 >> 2) & 1);
        int l1 = ((j1 & 1) << 2) | (j1 & 2) | ((j1 >> 2) & 1);
        float ex0a = __shfl(avx, l0, 64),      ey0a = __shfl(avy, l0, 64);
        float ex1a = __shfl(avx, l1, 64),      ey1a = __shfl(avy, l1, 64);
        float ex0b = __shfl(avx, 32 + l0, 64), ey0b = __shfl(avy, 32 + l0, 64);
        float ex1b = __shfl(avx, 32 + l1, 64), ey1b = __shfl(avy, 32 + l1, 64);
        float inv0a = (p & 1) ? ey0a : ex0a;
        float inv1a = (p & 1) ? ey1a : ex1a;
        float inv0b = (p & 1) ? ey0b : ex0b;
        float inv1b = (p & 1) ? ey1b : ex1b;
        if (p == 7) { inv1a = bb[(size_t)n0 * 20 + 0]; inv1b = bb[(size_t)n1 * 20 + 0]; }
        float wq0 = sWg[o0 * 34 + p],       wq1 = sWg[o0 * 34 + p + 8];
        float wr0 = sWg[(o0 + 1) * 34 + p], wr1 = sWg[(o0 + 1) * 34 + p + 8];
        float s0a = inv0a * wq0 + inv1a * wq1;
        float s1a = inv0a * wr0 + inv1a * wr1;
        float s0b = inv0b * wq0 + inv1b * wq1;
        float s1b = inv0b * wr0 + inv1b * wr1;
#pragma unroll
        for (int i = 2; i < 5; i++) {
            int k = p + 8 * i;
            if (k < 34) {
                float ia = bb[(size_t)n0 * 20 + (k - 15)];
                float ib2 = bb[(size_t)n1 * 20 + (k - 15)];
                float w0 = sWg[o0 * 34 + k], w1 = sWg[(o0 + 1) * 34 + k];
                s0a += ia * w0; s1a += ia * w1;
                s0b += ib2 * w0; s1b += ib2 * w1;
            }
        }
        s0a += __shfl_xor(s0a, 8, 64);  s1a += __shfl_xor(s1a, 8, 64);
        s0a += __shfl_xor(s0a, 16, 64); s1a += __shfl_xor(s1a, 16, 64);
        s0a += __shfl_xor(s0a, 32, 64); s1a += __shfl_xor(s1a, 32, 64);
        s0b += __shfl_xor(s0b, 8, 64);  s1b += __shfl_xor(s1b, 8, 64);
        s0b += __shfl_xor(s0b, 16, 64); s1b += __shfl_xor(s1b, 16, 64);
        s0b += __shfl_xor(s0b, 32, 64); s1b += __shfl_xor(s1b, 32, 64);
        if (p == 0) {
            ((unsigned*)h_out)[(size_t)n0 * 8 + c2e] = pkh(s0a * dn0, s1a * dn0);
            ((unsigned*)h_out)[(size_t)n1 * 8 + c2e] = pkh(s0b * dn1, s1b * dn1);
        }
    } else {
        float c = 0.0f;
        if (lg < 8) c = avx * sW3[2 * pr] + avy * sW3[2 * pr + 1];   // sW3[15]==0
        c += __shfl_xor(c, 1, 64);
        c += __shfl_xor(c, 2, 64);
        c += __shfl_xor(c, 4, 64);        // lane0 = node0 sum, lane32 = node1 sum
        c += __shfl_xor(c, 32, 64);       // combine groups
        if (lane == 0) ws2[wid] = c;
        __syncthreads();
        if (t == 0) {
            float s = 0.0f;
#pragma unroll
            for (int k = 0; k < 16; k++) s += ws2[k];
            atomicAdd(&bins[blockIdx.x & 63], s);
        }
    }
}

__global__ void k_finalize(const float* __restrict__ bins, const float* __restrict__ b3,
                           float* __restrict__ out) {
    float s = 0.0f;
    for (int k = 0; k < 64; k++) s += bins[k];
    out[0] = tanhf(s * (1.0f / (float)N_NODES) + b3[0]);
}

// ---------------------------------------------------------------------------
extern "C" void kernel_launch(void* const* d_in, const int* in_sizes, int n_in,
                              void* d_out, int out_size, void* d_ws, size_t ws_size,
                              hipStream_t stream) {
    const float* x1 = (const float*)d_in[0];
    const float* x2 = (const float*)d_in[1];
    const int* edges = (const int*)d_in[2];
    const float* W1 = (const float*)d_in[3];
    const float* b1 = (const float*)d_in[4];
    const float* Wg = (const float*)d_in[5];
    const float* bg = (const float*)d_in[6];
    const float* W3 = (const float*)d_in[7];
    const float* b3 = (const float*)d_in[8];
    const float* W4 = (const float*)d_in[9];
    const float* b4 = (const float*)d_in[10];

    const int* row = edges;             // edges[0]
    const int* col = edges + N_EDGES;   // edges[1]

    // workspace layout — ~30 MB (h0/h1 fp16: 3.2 MB each).
    char* ws = (char*)d_ws;
    unsigned* csr  = (unsigned*)ws;                              // NBKT*CAPB  (14.81 MB)
    float*    bb   = (float*)(csr + (size_t)NBKT * CAPB);        // N*20 f32   (8.0 MB)
    __half*   h0   = (__half*)(bb + (size_t)N_NODES * 20);       // N*16 fp16  (3.2 MB)
    __half*   h1   = h0 + (size_t)N_NODES * 16;                  // N*16 fp16  (3.2 MB)
    float*    dinv = (float*)(h1 + (size_t)N_NODES * 16);        // N
    int*      rs   = (int*)(dinv + N_NODES);                     // N
    int*      re   = rs + N_NODES;                               // N
    int*      gcur = re + N_NODES;                               // NBKT
    float*    bins = (float*)(gcur + NBKT);                      // 64

    int gN = (N_NODES + 255) / 256;                              // 391

    k_initg<<<1, 512, 0, stream>>>(gcur, bins);
    k_bucket<<<GEB, 512, 0, stream>>>(row, col, gcur, csr);
    k_sort<<<NBKT, 1024, 0, stream>>>(gcur, csr, rs, re, dinv);
    k_ab_h<<<gN, 256, 0, stream>>>(x1, x2, W1, b1, W4, b4, Wg, W3, dinv, bb, h0, bins);
    for (int t = 0; t < 5; t++) {
        const __half* hi = (t & 1) ? h1 : h0;
        __half* ho = (t & 1) ? h0 : h1;
        k_gather<<<N_NODES / 32, 1024, 0, stream>>>(rs, re, csr, hi, dinv, bb, Wg, bg, W3,
                                                    ho, bins, t == 4 ? 1 : 0);
    }
    k_finalize<<<1, 1, 0, stream>>>(bins, b3, (float*)d_out);
}